// Round 2
// baseline (1122.958 us; speedup 1.0000x reference)
//
#include <hip/hip_runtime.h>
#include <hip/hip_bf16.h>

// Problem constants (from reference): N=100000, F_IN=HID=256, E=800000, G=256
#define HID 256
#define NGRAPH 256

// ---------------------------------------------------------------------------
// CSR build (no hipMemsetAsync: zero via kernel; rowptr via deterministic scan)
// ---------------------------------------------------------------------------
__global__ void zero_int_kernel(int* __restrict__ p, int n) {
    int i = blockIdx.x * blockDim.x + threadIdx.x;
    if (i < n) p[i] = 0;
}

__global__ void count_deg_kernel(const int* __restrict__ ei, int E, int* __restrict__ deg) {
    int e = blockIdx.x * blockDim.x + threadIdx.x;
    if (e >= E) return;
    int dst = ei[E + e];
    atomicAdd(&deg[dst], 1);
}

// Single-block deterministic exclusive scan over deg -> rowptr, cursor, invd.
#define SCAN_T 256
__global__ __launch_bounds__(SCAN_T) void scan_rowptr_kernel(
    const int* __restrict__ deg, int N,
    int* __restrict__ rowptr, int* __restrict__ cursor, float* __restrict__ invd) {
    __shared__ int csum[SCAN_T];
    int t = threadIdx.x;
    int chunk = (N + SCAN_T - 1) / SCAN_T;
    int s = t * chunk;
    int e = min(N, s + chunk);
    int sum = 0;
    for (int i = s; i < e; ++i) sum += deg[i];
    csum[t] = sum;
    __syncthreads();
    int run = 0;
    for (int k = 0; k < t; ++k) run += csum[k];
    for (int i = s; i < e; ++i) {
        int d = deg[i];
        rowptr[i] = run;
        cursor[i] = run;
        invd[i] = rsqrtf((float)d + 1.0f);
        run += d;
    }
}

__global__ void fill_csr_kernel(const int* __restrict__ ei, int E,
                                int* __restrict__ cursor, int* __restrict__ csr_src) {
    int e = blockIdx.x * blockDim.x + threadIdx.x;
    if (e >= E) return;
    int src = ei[e];
    int dst = ei[E + e];
    int pos = atomicAdd(&cursor[dst], 1);
    csr_src[pos] = src;
}

// ---------------------------------------------------------------------------
// fp32 GEMM: out[i,:] = (X[i,:] @ W) * rowscale[i]   (X: Nx256, W: 256x256)
// 64x64 tile per 256-thread block, 4x4 micro-tile per thread.
// ---------------------------------------------------------------------------
#define TM 64
#define TN 64
#define KB 16
#define APAD 4
#define BPAD 4

__global__ __launch_bounds__(256) void gemm_rowscale_kernel(
    const float* __restrict__ X, const float* __restrict__ W,
    const float* __restrict__ rowscale, float* __restrict__ out, int Nrows) {
    __shared__ float As[KB][TM + APAD];  // As[kk][m]  (transposed stage)
    __shared__ float Bs[KB][TN + BPAD];  // Bs[kk][n]

    const int row0 = blockIdx.x * TM;
    const int col0 = blockIdx.y * TN;
    const int tid = threadIdx.x;
    const int tx = tid & 15;       // 0..15 -> col group
    const int ty = tid >> 4;       // 0..15 -> row group

    const int ar = tid >> 2;        // 0..63
    const int ak = (tid & 3) * 4;   // 0,4,8,12
    const int bk = tid >> 4;        // 0..15
    const int bc = (tid & 15) * 4;  // 0..60

    float acc[4][4] = {};

    for (int k0 = 0; k0 < 256; k0 += KB) {
        float4 av;
        if (row0 + ar < Nrows)
            av = *(const float4*)&X[(size_t)(row0 + ar) * 256 + k0 + ak];
        else
            av = make_float4(0.f, 0.f, 0.f, 0.f);
        As[ak + 0][ar] = av.x;
        As[ak + 1][ar] = av.y;
        As[ak + 2][ar] = av.z;
        As[ak + 3][ar] = av.w;

        float4 bv = *(const float4*)&W[(size_t)(k0 + bk) * 256 + col0 + bc];
        *(float4*)&Bs[bk][bc] = bv;

        __syncthreads();

#pragma unroll
        for (int kk = 0; kk < KB; ++kk) {
            float4 a4 = *(const float4*)&As[kk][ty * 4];
            float4 b4 = *(const float4*)&Bs[kk][tx * 4];
            float a[4] = {a4.x, a4.y, a4.z, a4.w};
            float b[4] = {b4.x, b4.y, b4.z, b4.w};
#pragma unroll
            for (int m = 0; m < 4; ++m)
#pragma unroll
                for (int n = 0; n < 4; ++n)
                    acc[m][n] = fmaf(a[m], b[n], acc[m][n]);
        }
        __syncthreads();
    }

#pragma unroll
    for (int m = 0; m < 4; ++m) {
        int r = row0 + ty * 4 + m;
        if (r < Nrows) {
            float sc = rowscale[r];
            float4 o;
            o.x = acc[m][0] * sc;
            o.y = acc[m][1] * sc;
            o.z = acc[m][2] * sc;
            o.w = acc[m][3] * sc;
            *(float4*)&out[(size_t)r * 256 + col0 + tx * 4] = o;
        }
    }
}

// ---------------------------------------------------------------------------
// Aggregation: out[i,:] = relu( inv_d[i] * (hs[i,:] + sum_{src->i} hs[src,:]) + b )
// One wave (64 lanes) per node; lane owns 4 contiguous floats.
// ---------------------------------------------------------------------------
__global__ __launch_bounds__(256) void gcn_aggregate_kernel(
    const float* __restrict__ hs, const int* __restrict__ rowptr,
    const int* __restrict__ deg, const int* __restrict__ csr_src,
    const float* __restrict__ inv_d, const float* __restrict__ bias,
    float* __restrict__ out, int N) {
    int gwid = (blockIdx.x * blockDim.x + threadIdx.x) >> 6;
    int lane = threadIdx.x & 63;
    if (gwid >= N) return;
    int c = lane * 4;
    int base = rowptr[gwid];
    int len = deg[gwid];

    float4 acc = *(const float4*)&hs[(size_t)gwid * 256 + c];
    for (int i = 0; i < len; ++i) {
        int s = csr_src[base + i];
        float4 v = *(const float4*)&hs[(size_t)s * 256 + c];
        acc.x += v.x;
        acc.y += v.y;
        acc.z += v.z;
        acc.w += v.w;
    }
    float sc = inv_d[gwid];
    float4 bb = *(const float4*)&bias[c];
    float4 o;
    o.x = fmaxf(fmaf(acc.x, sc, bb.x), 0.f);
    o.y = fmaxf(fmaf(acc.y, sc, bb.y), 0.f);
    o.z = fmaxf(fmaf(acc.z, sc, bb.z), 0.f);
    o.w = fmaxf(fmaf(acc.w, sc, bb.w), 0.f);
    *(float4*)&out[(size_t)gwid * 256 + c] = o;
}

// ---------------------------------------------------------------------------
// Graph boundaries from sorted batch: gstart[g] = first i with batch[i] >= g
// ---------------------------------------------------------------------------
__global__ void graph_bounds_kernel(const int* __restrict__ batch, int N, int G,
                                    int* __restrict__ gstart) {
    int i = blockIdx.x * blockDim.x + threadIdx.x;
    if (i > N) return;
    int cur = (i < N) ? batch[i] : G;
    int prev = (i == 0) ? -1 : batch[i - 1];
    for (int g = prev + 1; g <= cur; ++g) gstart[g] = i;
}

// One block per graph; thread j owns column j. Coalesced reads.
__global__ __launch_bounds__(256) void pool_mean_kernel(
    const float* __restrict__ emb, const int* __restrict__ gstart,
    float* __restrict__ gemb) {
    int g = blockIdx.x;
    int j = threadIdx.x;
    int s = gstart[g], e = gstart[g + 1];
    float sum = 0.f;
    for (int n = s; n < e; ++n) sum += emb[(size_t)n * 256 + j];
    float cnt = fmaxf((float)(e - s), 1.0f);
    gemb[g * 256 + j] = sum / cnt;
}

// hcls = relu(gemb @ Wc1 + bc1); Wc1 is (256,128) row-major
__global__ __launch_bounds__(128) void cls1_kernel(
    const float* __restrict__ gemb, const float* __restrict__ Wc1,
    const float* __restrict__ bc1, float* __restrict__ hcls) {
    int g = blockIdx.x;
    int j = threadIdx.x;  // 0..127
    float sum = bc1[j];
    for (int k = 0; k < 256; ++k) sum = fmaf(gemb[g * 256 + k], Wc1[k * 128 + j], sum);
    hcls[g * 128 + j] = fmaxf(sum, 0.f);
}

// logits = hcls @ Wc2 + bc2; Wc2 is (128,2) row-major
__global__ void cls2_kernel(const float* __restrict__ hcls, const float* __restrict__ Wc2,
                            const float* __restrict__ bc2, float* __restrict__ logits, int G) {
    int idx = blockIdx.x * blockDim.x + threadIdx.x;
    if (idx >= G * 2) return;
    int g = idx >> 1, c = idx & 1;
    float sum = bc2[c];
    for (int k = 0; k < 128; ++k) sum = fmaf(hcls[g * 128 + k], Wc2[k * 2 + c], sum);
    logits[idx] = sum;
}

// ---------------------------------------------------------------------------
extern "C" void kernel_launch(void* const* d_in, const int* in_sizes, int n_in,
                              void* d_out, int out_size, void* d_ws, size_t ws_size,
                              hipStream_t stream) {
    const float* x   = (const float*)d_in[0];
    const int*   ei  = (const int*)d_in[1];
    const int*   batch = (const int*)d_in[2];
    // d_in[3] = num_graphs (device scalar) — known statically: 256
    const float* W1  = (const float*)d_in[4];
    const float* b1  = (const float*)d_in[5];
    const float* W2  = (const float*)d_in[6];
    const float* b2  = (const float*)d_in[7];
    const float* Wc1 = (const float*)d_in[8];
    const float* bc1 = (const float*)d_in[9];
    const float* Wc2 = (const float*)d_in[10];
    const float* bc2 = (const float*)d_in[11];

    const int N = in_sizes[0] / HID;   // 100000
    const int E = in_sizes[1] / 2;     // 800000
    const int G = NGRAPH;              // 256

    float* logits   = (float*)d_out;                  // G*2
    float* node_out = (float*)d_out + (size_t)G * 2;  // N*HID (also holds layer-1 h)

    // workspace layout
    char* wsb = (char*)d_ws;
    size_t off = 0;
    auto alloc = [&](size_t bytes) -> void* {
        void* p = wsb + off;
        off += (bytes + 255) & ~(size_t)255;
        return p;
    };
    float* hs     = (float*)alloc((size_t)N * HID * 4);  // 102.4 MB
    int*   rowptr = (int*)alloc((size_t)N * 4);
    int*   cursor = (int*)alloc((size_t)N * 4);
    int*   degi   = (int*)alloc((size_t)N * 4);
    int*   csr    = (int*)alloc((size_t)E * 4);
    float* invd   = (float*)alloc((size_t)N * 4);
    int*   gstart = (int*)alloc((size_t)(G + 1) * 4);
    float* gemb   = (float*)alloc((size_t)G * HID * 4);
    float* hcls   = (float*)alloc((size_t)G * (HID / 2) * 4);
    (void)ws_size; (void)n_in; (void)out_size;

    // ---- CSR build (all compute-kernel path; no memset nodes in the graph) ----
    zero_int_kernel<<<(N + 255) / 256, 256, 0, stream>>>(degi, N);
    count_deg_kernel<<<(E + 255) / 256, 256, 0, stream>>>(ei, E, degi);
    scan_rowptr_kernel<<<1, SCAN_T, 0, stream>>>(degi, N, rowptr, cursor, invd);
    fill_csr_kernel<<<(E + 255) / 256, 256, 0, stream>>>(ei, E, cursor, csr);

    dim3 ggrid((N + TM - 1) / TM, HID / TN);

    // ---- layer 1 ----
    gemm_rowscale_kernel<<<ggrid, 256, 0, stream>>>(x, W1, invd, hs, N);
    gcn_aggregate_kernel<<<(N * 64 + 255) / 256, 256, 0, stream>>>(
        hs, rowptr, degi, csr, invd, b1, node_out, N);   // node_out temporarily = h

    // ---- layer 2 ----
    gemm_rowscale_kernel<<<ggrid, 256, 0, stream>>>(node_out, W2, invd, hs, N);
    gcn_aggregate_kernel<<<(N * 64 + 255) / 256, 256, 0, stream>>>(
        hs, rowptr, degi, csr, invd, b2, node_out, N);   // overwrites h with node_emb

    // ---- pooling + classifier ----
    graph_bounds_kernel<<<(N + 1 + 255) / 256, 256, 0, stream>>>(batch, N, G, gstart);
    pool_mean_kernel<<<G, 256, 0, stream>>>(node_out, gstart, gemb);
    cls1_kernel<<<G, 128, 0, stream>>>(gemb, Wc1, bc1, hcls);
    cls2_kernel<<<(G * 2 + 255) / 256, 256, 0, stream>>>(hcls, Wc2, bc2, logits, G);
}

// Round 3
// 852.041 us; speedup vs baseline: 1.3180x; 1.3180x over previous
//
#include <hip/hip_runtime.h>
#include <hip/hip_bf16.h>

// Problem constants (from reference): N=100000, F_IN=HID=256, E=800000, G=256
#define HID 256
#define NGRAPH 256

// ---------------------------------------------------------------------------
// CSR build (no hipMemsetAsync: zero via kernel; rowptr via parallel 3-pass scan)
// ---------------------------------------------------------------------------
__global__ void zero_int_kernel(int* __restrict__ p, int n) {
    int i = blockIdx.x * blockDim.x + threadIdx.x;
    if (i < n) p[i] = 0;
}

__global__ void count_deg_kernel(const int* __restrict__ ei, int E, int* __restrict__ deg) {
    int e = blockIdx.x * blockDim.x + threadIdx.x;
    if (e >= E) return;
    int dst = ei[E + e];
    atomicAdd(&deg[dst], 1);
}

// ---- hierarchical exclusive scan over deg (chunk = 512 per block) ----
#define SCHUNK 512

__global__ __launch_bounds__(256) void scan_pass1_kernel(
    const int* __restrict__ deg, int N, int* __restrict__ bsum) {
    __shared__ int red[256];
    int b = blockIdx.x, t = threadIdx.x;
    int i0 = b * SCHUNK + 2 * t;
    int v = 0;
    if (i0 < N) v += deg[i0];
    if (i0 + 1 < N) v += deg[i0 + 1];
    red[t] = v;
    __syncthreads();
    for (int s = 128; s > 0; s >>= 1) {
        if (t < s) red[t] += red[t + s];
        __syncthreads();
    }
    if (t == 0) bsum[b] = red[0];
}

// single block: exclusive scan over NB (<=256) block sums
__global__ __launch_bounds__(256) void scan_pass2_kernel(
    const int* __restrict__ bsum, int NB, int* __restrict__ boff) {
    __shared__ int s[256];
    int t = threadIdx.x;
    int v = (t < NB) ? bsum[t] : 0;
    s[t] = v;
    __syncthreads();
    for (int off = 1; off < 256; off <<= 1) {
        int x = s[t];
        if (t >= off) x += s[t - off];
        __syncthreads();
        s[t] = x;
        __syncthreads();
    }
    if (t < NB) boff[t] = s[t] - v;  // exclusive
}

__global__ __launch_bounds__(256) void scan_pass3_kernel(
    const int* __restrict__ deg, int N, const int* __restrict__ boff,
    int* __restrict__ rowptr, int* __restrict__ cursor, float* __restrict__ invd) {
    __shared__ int s[256];
    int b = blockIdx.x, t = threadIdx.x;
    int i0 = b * SCHUNK + 2 * t;
    int d0 = (i0 < N) ? deg[i0] : 0;
    int d1 = (i0 + 1 < N) ? deg[i0 + 1] : 0;
    int pair = d0 + d1;
    s[t] = pair;
    __syncthreads();
    for (int off = 1; off < 256; off <<= 1) {
        int x = s[t];
        if (t >= off) x += s[t - off];
        __syncthreads();
        s[t] = x;
        __syncthreads();
    }
    int excl = s[t] - pair + boff[b];
    if (i0 < N) {
        rowptr[i0] = excl;
        cursor[i0] = excl;
        invd[i0] = rsqrtf((float)d0 + 1.0f);
    }
    if (i0 + 1 < N) {
        int e1 = excl + d0;
        rowptr[i0 + 1] = e1;
        cursor[i0 + 1] = e1;
        invd[i0 + 1] = rsqrtf((float)d1 + 1.0f);
    }
}

__global__ void fill_csr_kernel(const int* __restrict__ ei, int E,
                                int* __restrict__ cursor, int* __restrict__ csr_src) {
    int e = blockIdx.x * blockDim.x + threadIdx.x;
    if (e >= E) return;
    int src = ei[e];
    int dst = ei[E + e];
    int pos = atomicAdd(&cursor[dst], 1);
    csr_src[pos] = src;
}

// ---------------------------------------------------------------------------
// fp32 GEMM: out[i,:] = (X[i,:] @ W) * rowscale[i]   (X: Nx256, W: 256x256)
// 64x64 tile per 256-thread block, 4x4 micro-tile per thread.
// ---------------------------------------------------------------------------
#define TM 64
#define TN 64
#define KB 16
#define APAD 4
#define BPAD 4

__global__ __launch_bounds__(256) void gemm_rowscale_kernel(
    const float* __restrict__ X, const float* __restrict__ W,
    const float* __restrict__ rowscale, float* __restrict__ out, int Nrows) {
    __shared__ float As[KB][TM + APAD];  // As[kk][m]  (transposed stage)
    __shared__ float Bs[KB][TN + BPAD];  // Bs[kk][n]

    const int row0 = blockIdx.x * TM;
    const int col0 = blockIdx.y * TN;
    const int tid = threadIdx.x;
    const int tx = tid & 15;       // 0..15 -> col group
    const int ty = tid >> 4;       // 0..15 -> row group

    const int ar = tid >> 2;        // 0..63
    const int ak = (tid & 3) * 4;   // 0,4,8,12
    const int bk = tid >> 4;        // 0..15
    const int bc = (tid & 15) * 4;  // 0..60

    float acc[4][4] = {};

    for (int k0 = 0; k0 < 256; k0 += KB) {
        float4 av;
        if (row0 + ar < Nrows)
            av = *(const float4*)&X[(size_t)(row0 + ar) * 256 + k0 + ak];
        else
            av = make_float4(0.f, 0.f, 0.f, 0.f);
        As[ak + 0][ar] = av.x;
        As[ak + 1][ar] = av.y;
        As[ak + 2][ar] = av.z;
        As[ak + 3][ar] = av.w;

        float4 bv = *(const float4*)&W[(size_t)(k0 + bk) * 256 + col0 + bc];
        *(float4*)&Bs[bk][bc] = bv;

        __syncthreads();

#pragma unroll
        for (int kk = 0; kk < KB; ++kk) {
            float4 a4 = *(const float4*)&As[kk][ty * 4];
            float4 b4 = *(const float4*)&Bs[kk][tx * 4];
            float a[4] = {a4.x, a4.y, a4.z, a4.w};
            float b[4] = {b4.x, b4.y, b4.z, b4.w};
#pragma unroll
            for (int m = 0; m < 4; ++m)
#pragma unroll
                for (int n = 0; n < 4; ++n)
                    acc[m][n] = fmaf(a[m], b[n], acc[m][n]);
        }
        __syncthreads();
    }

#pragma unroll
    for (int m = 0; m < 4; ++m) {
        int r = row0 + ty * 4 + m;
        if (r < Nrows) {
            float sc = rowscale[r];
            float4 o;
            o.x = acc[m][0] * sc;
            o.y = acc[m][1] * sc;
            o.z = acc[m][2] * sc;
            o.w = acc[m][3] * sc;
            *(float4*)&out[(size_t)r * 256 + col0 + tx * 4] = o;
        }
    }
}

// ---------------------------------------------------------------------------
// Aggregation: out[i,:] = relu( inv_d[i] * (hs[i,:] + sum_{src->i} hs[src,:]) + b )
// One wave (64 lanes) per node; lane owns 4 contiguous floats.
// ---------------------------------------------------------------------------
__global__ __launch_bounds__(256) void gcn_aggregate_kernel(
    const float* __restrict__ hs, const int* __restrict__ rowptr,
    const int* __restrict__ deg, const int* __restrict__ csr_src,
    const float* __restrict__ inv_d, const float* __restrict__ bias,
    float* __restrict__ out, int N) {
    int gwid = (blockIdx.x * blockDim.x + threadIdx.x) >> 6;
    int lane = threadIdx.x & 63;
    if (gwid >= N) return;
    int c = lane * 4;
    int base = rowptr[gwid];
    int len = deg[gwid];

    float4 acc = *(const float4*)&hs[(size_t)gwid * 256 + c];
    for (int i = 0; i < len; ++i) {
        int s = csr_src[base + i];
        float4 v = *(const float4*)&hs[(size_t)s * 256 + c];
        acc.x += v.x;
        acc.y += v.y;
        acc.z += v.z;
        acc.w += v.w;
    }
    float sc = inv_d[gwid];
    float4 bb = *(const float4*)&bias[c];
    float4 o;
    o.x = fmaxf(fmaf(acc.x, sc, bb.x), 0.f);
    o.y = fmaxf(fmaf(acc.y, sc, bb.y), 0.f);
    o.z = fmaxf(fmaf(acc.z, sc, bb.z), 0.f);
    o.w = fmaxf(fmaf(acc.w, sc, bb.w), 0.f);
    *(float4*)&out[(size_t)gwid * 256 + c] = o;
}

// ---------------------------------------------------------------------------
// Graph boundaries from sorted batch: gstart[g] = first i with batch[i] >= g
// ---------------------------------------------------------------------------
__global__ void graph_bounds_kernel(const int* __restrict__ batch, int N, int G,
                                    int* __restrict__ gstart) {
    int i = blockIdx.x * blockDim.x + threadIdx.x;
    if (i > N) return;
    int cur = (i < N) ? batch[i] : G;
    int prev = (i == 0) ? -1 : batch[i - 1];
    for (int g = prev + 1; g <= cur; ++g) gstart[g] = i;
}

// One block per graph; thread j owns column j. Coalesced reads.
__global__ __launch_bounds__(256) void pool_mean_kernel(
    const float* __restrict__ emb, const int* __restrict__ gstart,
    float* __restrict__ gemb) {
    int g = blockIdx.x;
    int j = threadIdx.x;
    int s = gstart[g], e = gstart[g + 1];
    float sum = 0.f;
    for (int n = s; n < e; ++n) sum += emb[(size_t)n * 256 + j];
    float cnt = fmaxf((float)(e - s), 1.0f);
    gemb[g * 256 + j] = sum / cnt;
}

// hcls = relu(gemb @ Wc1 + bc1); Wc1 is (256,128) row-major
__global__ __launch_bounds__(128) void cls1_kernel(
    const float* __restrict__ gemb, const float* __restrict__ Wc1,
    const float* __restrict__ bc1, float* __restrict__ hcls) {
    int g = blockIdx.x;
    int j = threadIdx.x;  // 0..127
    float sum = bc1[j];
    for (int k = 0; k < 256; ++k) sum = fmaf(gemb[g * 256 + k], Wc1[k * 128 + j], sum);
    hcls[g * 128 + j] = fmaxf(sum, 0.f);
}

// logits = hcls @ Wc2 + bc2; Wc2 is (128,2) row-major
__global__ void cls2_kernel(const float* __restrict__ hcls, const float* __restrict__ Wc2,
                            const float* __restrict__ bc2, float* __restrict__ logits, int G) {
    int idx = blockIdx.x * blockDim.x + threadIdx.x;
    if (idx >= G * 2) return;
    int g = idx >> 1, c = idx & 1;
    float sum = bc2[c];
    for (int k = 0; k < 128; ++k) sum = fmaf(hcls[g * 128 + k], Wc2[k * 2 + c], sum);
    logits[idx] = sum;
}

// ---------------------------------------------------------------------------
extern "C" void kernel_launch(void* const* d_in, const int* in_sizes, int n_in,
                              void* d_out, int out_size, void* d_ws, size_t ws_size,
                              hipStream_t stream) {
    const float* x   = (const float*)d_in[0];
    const int*   ei  = (const int*)d_in[1];
    const int*   batch = (const int*)d_in[2];
    // d_in[3] = num_graphs (device scalar) — known statically: 256
    const float* W1  = (const float*)d_in[4];
    const float* b1  = (const float*)d_in[5];
    const float* W2  = (const float*)d_in[6];
    const float* b2  = (const float*)d_in[7];
    const float* Wc1 = (const float*)d_in[8];
    const float* bc1 = (const float*)d_in[9];
    const float* Wc2 = (const float*)d_in[10];
    const float* bc2 = (const float*)d_in[11];

    const int N = in_sizes[0] / HID;   // 100000
    const int E = in_sizes[1] / 2;     // 800000
    const int G = NGRAPH;              // 256

    float* logits   = (float*)d_out;                  // G*2
    float* node_out = (float*)d_out + (size_t)G * 2;  // N*HID (also holds layer-1 h)

    // workspace layout
    char* wsb = (char*)d_ws;
    size_t off = 0;
    auto alloc = [&](size_t bytes) -> void* {
        void* p = wsb + off;
        off += (bytes + 255) & ~(size_t)255;
        return p;
    };
    float* hs     = (float*)alloc((size_t)N * HID * 4);  // 102.4 MB
    int*   rowptr = (int*)alloc((size_t)N * 4);
    int*   cursor = (int*)alloc((size_t)N * 4);
    int*   degi   = (int*)alloc((size_t)N * 4);
    int*   csr    = (int*)alloc((size_t)E * 4);
    float* invd   = (float*)alloc((size_t)N * 4);
    int*   gstart = (int*)alloc((size_t)(G + 1) * 4);
    float* gemb   = (float*)alloc((size_t)G * HID * 4);
    float* hcls   = (float*)alloc((size_t)G * (HID / 2) * 4);
    int*   bsum   = (int*)alloc(256 * 4);
    int*   boff   = (int*)alloc(256 * 4);
    (void)ws_size; (void)n_in; (void)out_size;

    const int NB = (N + SCHUNK - 1) / SCHUNK;  // 196 scan blocks

    // ---- CSR build (all compute-kernel path; no memset nodes in the graph) ----
    zero_int_kernel<<<(N + 255) / 256, 256, 0, stream>>>(degi, N);
    count_deg_kernel<<<(E + 255) / 256, 256, 0, stream>>>(ei, E, degi);
    scan_pass1_kernel<<<NB, 256, 0, stream>>>(degi, N, bsum);
    scan_pass2_kernel<<<1, 256, 0, stream>>>(bsum, NB, boff);
    scan_pass3_kernel<<<NB, 256, 0, stream>>>(degi, N, boff, rowptr, cursor, invd);
    fill_csr_kernel<<<(E + 255) / 256, 256, 0, stream>>>(ei, E, cursor, csr);

    dim3 ggrid((N + TM - 1) / TM, HID / TN);

    // ---- layer 1 ----
    gemm_rowscale_kernel<<<ggrid, 256, 0, stream>>>(x, W1, invd, hs, N);
    gcn_aggregate_kernel<<<(N * 64 + 255) / 256, 256, 0, stream>>>(
        hs, rowptr, degi, csr, invd, b1, node_out, N);   // node_out temporarily = h

    // ---- layer 2 ----
    gemm_rowscale_kernel<<<ggrid, 256, 0, stream>>>(node_out, W2, invd, hs, N);
    gcn_aggregate_kernel<<<(N * 64 + 255) / 256, 256, 0, stream>>>(
        hs, rowptr, degi, csr, invd, b2, node_out, N);   // overwrites h with node_emb

    // ---- pooling + classifier ----
    graph_bounds_kernel<<<(N + 1 + 255) / 256, 256, 0, stream>>>(batch, N, G, gstart);
    pool_mean_kernel<<<G, 256, 0, stream>>>(node_out, gstart, gemb);
    cls1_kernel<<<G, 128, 0, stream>>>(gemb, Wc1, bc1, hcls);
    cls2_kernel<<<(G * 2 + 255) / 256, 256, 0, stream>>>(hcls, Wc2, bc2, logits, G);
}